// Round 7
// baseline (181.756 us; speedup 1.0000x reference)
//
#include <hip/hip_runtime.h>

// GeodesicAttention: B=4, T=2048, D=1024, R=32
//   y = x @ U; logits[t,j] = 2 y_t.y_j - n_j  (row-const -n_t cancels)
//   KEY: max_j logit = n_t exactly (2ab - b^2 <= a^2, equality j=t), so
//   p[t,j] = exp(2 y_t.y_j - n_j - n_t) in (0,1] with NO online max/rescale.
// Round 7: scores+PV fused — P never touches HBM (R6: scores wrote 32MB,
// latency-bound pv re-read it at MfmaUtil 19%). Per j-tile: stage xt tile
// (async, overlapped by QK^T+exp), P -> LDS, PV MFMAs. l in registers.
//   geo_ut    : Ut[r][d] = bf16(U[d][r])
//   geo_prep  : xt[b][d][t] = bf16(x) for its d-slab, y_part[s] = x_slab @ U
//   geo_reduce: y = sum_s y_part, ybf = bf16(sqrt2*y), nsq = |ybf|^2
//   geo_fused : out[t][d] = sum_j exp(2yy-nj-nt) x[j][d] / l[t]
#define B_ 4
#define T_ 2048
#define D_ 1024
#define R_ 32
#define XSTR2 136  // prep LDS row stride in shorts (272B = 17*16B; row width 128)
#define TT 64      // fused: t rows per block
#define TD 128     // fused: d cols per block
#define TJ 64      // fused: j per k-tile
#define PSTR 72    // fused: Pbuf row stride in shorts (144B, 16B-aligned)

typedef __attribute__((ext_vector_type(8))) short short8;
typedef __attribute__((ext_vector_type(4))) float f32x4;
typedef __attribute__((ext_vector_type(4))) unsigned short us4;
typedef __attribute__((ext_vector_type(8))) unsigned short us8;

__device__ __forceinline__ unsigned short f2bf(float f) {
  union { float f; unsigned u; } v; v.f = f;
  unsigned r = (v.u + 0x7fffu + ((v.u >> 16) & 1u)) >> 16;
  return (unsigned short)r;
}
__device__ __forceinline__ float bf2f(unsigned short h) {
  union { unsigned u; float f; } v; v.u = (unsigned)h << 16;
  return v.f;
}

// ---------------- Ut[r][d] = bf16(U[d][r]) ----------------
__global__ __launch_bounds__(256)
void geo_ut(const float* __restrict__ U, unsigned short* __restrict__ Ut) {
  __shared__ float tile[128][33];
  const int tid = threadIdx.x;
  const int d0 = blockIdx.x * 128;
  #pragma unroll
  for (int i = 0; i < 16; i++) {
    int e = i * 256 + tid;
    int d = e >> 5, r = e & 31;
    tile[d][r] = U[(size_t)(d0 + d) * R_ + r];
  }
  __syncthreads();
  const int r = tid >> 3, seg = tid & 7;
  us8 o0, o1;
  #pragma unroll
  for (int k = 0; k < 8; k++) o0[k] = f2bf(tile[seg * 16 + k][r]);
  #pragma unroll
  for (int k = 0; k < 8; k++) o1[k] = f2bf(tile[seg * 16 + 8 + k][r]);
  *(us8*)(Ut + (size_t)r * D_ + d0 + seg * 16) = o0;
  *(us8*)(Ut + (size_t)r * D_ + d0 + seg * 16 + 8) = o1;
}

// ---------------- prep: xt + partial y, one barrier, 4 blocks/CU ------------
__global__ __launch_bounds__(256)
void geo_prep(const float* __restrict__ x, const unsigned short* __restrict__ Ut,
              unsigned short* __restrict__ xt, float* __restrict__ y_part) {
  __shared__ unsigned short xs[2][32 * XSTR2];
  const int b = blockIdx.y, slab = blockIdx.z;
  const int t0 = blockIdx.x * 32;
  const int d0 = slab * 256;
  const int tid = threadIdx.x, w = tid >> 6, lane = tid & 63;
  const int m = lane & 15, quad = lane >> 4;
  const int Mt = w & 1, Nt = w >> 1;
  const int lr = tid >> 3;
  const int lc = (tid & 7) * 16;

  const float* xb = x + ((size_t)b * T_ + t0 + lr) * D_ + d0 + lc;
  float4 v[2][4];
  #pragma unroll
  for (int ch = 0; ch < 2; ch++)
    #pragma unroll
    for (int i = 0; i < 4; i++)
      v[ch][i] = *(const float4*)(xb + ch * 128 + i * 4);
  #pragma unroll
  for (int ch = 0; ch < 2; ch++)
    #pragma unroll
    for (int i = 0; i < 4; i++) {
      us4 c;
      c[0] = f2bf(v[ch][i].x); c[1] = f2bf(v[ch][i].y);
      c[2] = f2bf(v[ch][i].z); c[3] = f2bf(v[ch][i].w);
      *(us4*)&xs[ch][lr * XSTR2 + lc + i * 4] = c;
    }
  __syncthreads();
  {
    const int wd = tid >> 1, wt = (tid & 1) * 16;
    #pragma unroll
    for (int ch = 0; ch < 2; ch++) {
      us8 o0, o1;
      #pragma unroll
      for (int k = 0; k < 8; k++) {
        o0[k] = xs[ch][(wt + k) * XSTR2 + wd];
        o1[k] = xs[ch][(wt + 8 + k) * XSTR2 + wd];
      }
      unsigned short* xo = xt + ((size_t)b * D_ + d0 + ch * 128 + wd) * T_ + t0;
      *(us8*)(xo + wt) = o0;
      *(us8*)(xo + wt + 8) = o1;
    }
  }
  f32x4 acc = {0.f, 0.f, 0.f, 0.f};
  #pragma unroll
  for (int ch = 0; ch < 2; ch++)
    #pragma unroll
    for (int ks = 0; ks < 4; ks++) {
      short8 af = *(const short8*)&xs[ch][(Mt * 16 + m) * XSTR2 + ks * 32 + quad * 8];
      short8 bf = *(const short8*)(Ut + (size_t)(Nt * 16 + m) * D_ + d0 + ch * 128 + ks * 32 + quad * 8);
      acc = __builtin_amdgcn_mfma_f32_16x16x32_bf16(af, bf, acc, 0, 0, 0);
    }
  float* yp = y_part + ((size_t)(slab * B_ + b) * T_ + t0 + Mt * 16 + quad * 4) * R_ + Nt * 16 + m;
  #pragma unroll
  for (int k = 0; k < 4; k++) yp[(size_t)k * R_] = acc[k];
}

// ---------------- reduce: y = sum_s y_part; ybf, nsq ------------------------
__global__ __launch_bounds__(256)
void geo_reduce(const float* __restrict__ y_part, unsigned short* __restrict__ ybf,
                float* __restrict__ nsq) {
  const int tid = threadIdx.x;
  const size_t row = (size_t)blockIdx.x * 32 + (tid >> 3);
  const int r0 = (tid & 7) * 4;
  f32x4 v = {0.f, 0.f, 0.f, 0.f};
  #pragma unroll
  for (int s = 0; s < 4; s++) {
    f32x4 p = *(const f32x4*)(y_part + ((size_t)s * B_ * T_ + row) * R_ + r0);
    #pragma unroll
    for (int k = 0; k < 4; k++) v[k] += p[k];
  }
  us4 pk;
  float part = 0.f;
  #pragma unroll
  for (int k = 0; k < 4; k++) {
    pk[k] = f2bf(1.41421356237f * v[k]);
    float b = bf2f(pk[k]);             // exactly what fused will dot
    part += b * b;
  }
  *(us4*)(ybf + row * R_ + r0) = pk;
  part += __shfl_xor(part, 1, 64);
  part += __shfl_xor(part, 2, 64);
  part += __shfl_xor(part, 4, 64);
  if ((tid & 7) == 0) nsq[row] = 0.5f * part;
}

// ---------------- fused scores + PV ----------------
// grid (32 t-tiles * 8 d-tiles, 1, B); x&7 = d-tile so same-d blocks share an
// XCD's L2 for the xt tile. Per 64-j tile: async-stage xt (overlapped by QK),
// QK^T (wave w owns 16 j-cols), p=exp(c-nj-nt) -> Pbuf(LDS), 16 PV MFMAs.
__global__ __launch_bounds__(256)
void geo_fused(const unsigned short* __restrict__ ybf,
               const float* __restrict__ nsq,
               const unsigned short* __restrict__ xt,
               float* __restrict__ out) {
  __shared__ unsigned short XtS[TD * TJ];      // 16 KB, [d][slot^d] swizzled
  __shared__ unsigned short Pbuf[TT * PSTR];   // 9 KB, P rows (A-frag layout)
  __shared__ float lred[4][TT];                // per-wave row sums
  const int b = blockIdx.z;
  const int dt = blockIdx.x & 7, tt = blockIdx.x >> 3;
  const int t0 = tt * TT, d0 = dt * TD;
  const int tid = threadIdx.x, w = tid >> 6, lane = tid & 63;
  const int m = lane & 15, quad = lane >> 4;
  const int srow = lane >> 3, sslot = lane & 7;
  const unsigned short* yb = ybf + (size_t)b * T_ * R_;
  const float* nb = nsq + (size_t)b * T_;
  const unsigned short* xtb = xt + ((size_t)b * D_ + d0) * T_;

  short8 aq[4]; f32x4 ntv[4];
  #pragma unroll
  for (int s = 0; s < 4; s++) {
    aq[s]  = *(const short8*)(yb + (size_t)(t0 + s * 16 + m) * R_ + quad * 8);
    ntv[s] = *(const f32x4*)(nb + t0 + s * 16 + quad * 4);
  }
  f32x4 acc[4][2];
  f32x4 lsum[4];
  #pragma unroll
  for (int s = 0; s < 4; s++) {
    lsum[s] = (f32x4){0.f, 0.f, 0.f, 0.f};
    acc[s][0] = (f32x4){0.f, 0.f, 0.f, 0.f};
    acc[s][1] = (f32x4){0.f, 0.f, 0.f, 0.f};
  }

  for (int j0 = 0; j0 < T_; j0 += TJ) {
    if (j0) __syncthreads();   // prev PV done: safe to overwrite XtS/Pbuf
    // ---- stage xt tile (async; QK below overlaps the latency) ----
    #pragma unroll
    for (int cc = 0; cc < 4; cc++) {
      const int rd = w * 32 + cc * 8 + srow;
      const int gs = sslot ^ (rd & 7);
      __builtin_amdgcn_global_load_lds(
          (const __attribute__((address_space(1))) void*)(xtb + (size_t)rd * T_ + j0 + gs * 8),
          (__attribute__((address_space(3))) void*)(XtS + (w * 32 + cc * 8) * 64),
          16, 0, 0);
    }
    // ---- QK^T for this wave's 16 j cols; p -> Pbuf ----
    short8 bj = *(const short8*)(yb + (size_t)(j0 + w * 16 + m) * R_ + quad * 8);
    float nj = nb[j0 + w * 16 + m];
    #pragma unroll
    for (int s = 0; s < 4; s++) {
      f32x4 z = {0.f, 0.f, 0.f, 0.f};
      f32x4 c = __builtin_amdgcn_mfma_f32_16x16x32_bf16(aq[s], bj, z, 0, 0, 0);
      #pragma unroll
      for (int r = 0; r < 4; r++) {
        float p = __expf(c[r] - nj - ntv[s][r]);
        lsum[s][r] += p;
        Pbuf[(s * 16 + quad * 4 + r) * PSTR + w * 16 + m] = f2bf(p);
      }
    }
    __syncthreads();   // XtS staged (vmcnt drained) + Pbuf visible
    // ---- PV: acc[s][nt] += P[s-th 16t][64j] @ X[64j][w's nt-th 16d] ----
    short8 bx[2][2];
    #pragma unroll
    for (int nt = 0; nt < 2; nt++) {
      const int dloc = w * 32 + nt * 16 + m;
      #pragma unroll
      for (int ks = 0; ks < 2; ks++)
        bx[nt][ks] = *(const short8*)(XtS + dloc * 64 + (((ks * 4 + quad) ^ (m & 7)) * 8));
    }
    #pragma unroll
    for (int s = 0; s < 4; s++) {
      short8 a0 = *(const short8*)(Pbuf + (s * 16 + m) * PSTR + quad * 8);
      short8 a1 = *(const short8*)(Pbuf + (s * 16 + m) * PSTR + 32 + quad * 8);
      #pragma unroll
      for (int nt = 0; nt < 2; nt++) {
        acc[s][nt] = __builtin_amdgcn_mfma_f32_16x16x32_bf16(a0, bx[nt][0], acc[s][nt], 0, 0, 0);
        acc[s][nt] = __builtin_amdgcn_mfma_f32_16x16x32_bf16(a1, bx[nt][1], acc[s][nt], 0, 0, 0);
      }
    }
  }
  // ---- l: reduce over 16 m-lanes, then across waves via LDS ----
  #pragma unroll
  for (int s = 0; s < 4; s++)
    #pragma unroll
    for (int r = 0; r < 4; r++) {
      float v = lsum[s][r];
      v += __shfl_xor(v, 1, 64);
      v += __shfl_xor(v, 2, 64);
      v += __shfl_xor(v, 4, 64);
      v += __shfl_xor(v, 8, 64);
      lsum[s][r] = v;
    }
  if (m == 0) {
    #pragma unroll
    for (int s = 0; s < 4; s++)
      *(f32x4*)&lred[w][s * 16 + quad * 4] = lsum[s];
  }
  __syncthreads();
  float* ob = out + ((size_t)b * T_ + t0) * D_ + d0;
  #pragma unroll
  for (int s = 0; s < 4; s++) {
    f32x4 lt = *(const f32x4*)&lred[0][s * 16 + quad * 4];
    #pragma unroll
    for (int ww = 1; ww < 4; ww++) {
      f32x4 lv = *(const f32x4*)&lred[ww][s * 16 + quad * 4];
      #pragma unroll
      for (int r = 0; r < 4; r++) lt[r] += lv[r];
    }
    f32x4 inv;
    #pragma unroll
    for (int r = 0; r < 4; r++) inv[r] = 1.f / lt[r];
    #pragma unroll
    for (int nt = 0; nt < 2; nt++)
      #pragma unroll
      for (int r = 0; r < 4; r++)
        ob[(size_t)(s * 16 + quad * 4 + r) * D_ + w * 32 + nt * 16 + m] =
            acc[s][nt][r] * inv[r];
  }
}

extern "C" void kernel_launch(void* const* d_in, const int* in_sizes, int n_in,
                              void* d_out, int out_size, void* d_ws, size_t ws_size,
                              hipStream_t stream) {
  const float* x = (const float*)d_in[0];
  const float* U = (const float*)d_in[1];
  float* out = (float*)d_out;

  const size_t xt_b  = (size_t)B_ * D_ * T_ * 2;       // 16 MB
  const size_t ybf_b = (size_t)B_ * T_ * R_ * 2;       // 512 KB
  const size_t nsq_b = (size_t)B_ * T_ * 4;
  const size_t ut_b  = (size_t)D_ * R_ * 2;            // 64 KB
  const size_t yp_b  = (size_t)4 * B_ * T_ * R_ * 4;   // 4 MB

  char* wp = (char*)d_ws;
  unsigned short* xtp = (unsigned short*)wp;           wp += xt_b;
  unsigned short* ybf = (unsigned short*)wp;           wp += ybf_b;
  float* nsq = (float*)wp;                             wp += nsq_b;
  unsigned short* Utp = (unsigned short*)wp;           wp += ut_b;
  float* ypart = (float*)wp;                           wp += yp_b;
  (void)ws_size;

  hipLaunchKernelGGL(geo_ut, dim3(D_ / 128), dim3(256), 0, stream, U, Utp);
  hipLaunchKernelGGL(geo_prep, dim3(T_ / 32, B_, 4), dim3(256), 0, stream,
                     x, Utp, xtp, ypart);
  hipLaunchKernelGGL(geo_reduce, dim3(B_ * T_ / 32), dim3(256), 0, stream,
                     ypart, ybf, nsq);
  hipLaunchKernelGGL(geo_fused, dim3((T_ / TT) * (D_ / TD), 1, B_), dim3(256), 0, stream,
                     ybf, nsq, xtp, out);
}

// Round 8
// 158.552 us; speedup vs baseline: 1.1464x; 1.1464x over previous
//
#include <hip/hip_runtime.h>

// GeodesicAttention: B=4, T=2048, D=1024, R=32
//   y = x @ U; logits[t,j] = 2 y_t.y_j - n_j  (row-const -n_t cancels)
//   KEY: max_j logit = n_t exactly, so p = exp(2yy - nj - nt) in (0,1],
//   NO online max/rescale. Everything in exp2 units: ybf = bf16(sqrt(2*log2e)*y),
//   nsq = 0.5*|ybf|^2  ->  p = exp2(c - nj - nt), native v_exp_f32.
// Round 8 (fixing R7's measured VALU bound + 4-way conflicts):
//   - QK operand swap (A=Yj, B=Yt): lane owns 4 consecutive j for one t ->
//     packed us4 b64 P-writes (was 16 scalar b16 at 4-way conflict).
//   - exp2f instead of __expf (drops a v_mul per element).
//   - TD 128->256: halves the per-GPU exp/QK duplication (8x -> 4x).
#define B_ 4
#define T_ 2048
#define D_ 1024
#define R_ 32
#define XSTR2 136  // prep LDS row stride in shorts (272B = 17*16B; row width 128)
#define TT 64      // fused: t rows per block
#define TD 256     // fused: d cols per block
#define TJ 64      // fused: j per k-tile
#define PSTR 72    // fused: Pbuf row stride in shorts (144B, 16B-aligned)
#define S2L 1.6986436f  // sqrt(2*log2(e))

typedef __attribute__((ext_vector_type(8))) short short8;
typedef __attribute__((ext_vector_type(4))) float f32x4;
typedef __attribute__((ext_vector_type(4))) unsigned short us4;
typedef __attribute__((ext_vector_type(8))) unsigned short us8;

__device__ __forceinline__ unsigned short f2bf(float f) {
  union { float f; unsigned u; } v; v.f = f;
  unsigned r = (v.u + 0x7fffu + ((v.u >> 16) & 1u)) >> 16;
  return (unsigned short)r;
}
__device__ __forceinline__ float bf2f(unsigned short h) {
  union { unsigned u; float f; } v; v.u = (unsigned)h << 16;
  return v.f;
}

// ---------------- Ut[r][d] = bf16(U[d][r]) ----------------
__global__ __launch_bounds__(256)
void geo_ut(const float* __restrict__ U, unsigned short* __restrict__ Ut) {
  __shared__ float tile[128][33];
  const int tid = threadIdx.x;
  const int d0 = blockIdx.x * 128;
  #pragma unroll
  for (int i = 0; i < 16; i++) {
    int e = i * 256 + tid;
    int d = e >> 5, r = e & 31;
    tile[d][r] = U[(size_t)(d0 + d) * R_ + r];
  }
  __syncthreads();
  const int r = tid >> 3, seg = tid & 7;
  us8 o0, o1;
  #pragma unroll
  for (int k = 0; k < 8; k++) o0[k] = f2bf(tile[seg * 16 + k][r]);
  #pragma unroll
  for (int k = 0; k < 8; k++) o1[k] = f2bf(tile[seg * 16 + 8 + k][r]);
  *(us8*)(Ut + (size_t)r * D_ + d0 + seg * 16) = o0;
  *(us8*)(Ut + (size_t)r * D_ + d0 + seg * 16 + 8) = o1;
}

// ---------------- prep: xt + partial y, one barrier, 4 blocks/CU ------------
__global__ __launch_bounds__(256)
void geo_prep(const float* __restrict__ x, const unsigned short* __restrict__ Ut,
              unsigned short* __restrict__ xt, float* __restrict__ y_part) {
  __shared__ unsigned short xs[2][32 * XSTR2];
  const int b = blockIdx.y, slab = blockIdx.z;
  const int t0 = blockIdx.x * 32;
  const int d0 = slab * 256;
  const int tid = threadIdx.x, w = tid >> 6, lane = tid & 63;
  const int m = lane & 15, quad = lane >> 4;
  const int Mt = w & 1, Nt = w >> 1;
  const int lr = tid >> 3;
  const int lc = (tid & 7) * 16;

  const float* xb = x + ((size_t)b * T_ + t0 + lr) * D_ + d0 + lc;
  float4 v[2][4];
  #pragma unroll
  for (int ch = 0; ch < 2; ch++)
    #pragma unroll
    for (int i = 0; i < 4; i++)
      v[ch][i] = *(const float4*)(xb + ch * 128 + i * 4);
  #pragma unroll
  for (int ch = 0; ch < 2; ch++)
    #pragma unroll
    for (int i = 0; i < 4; i++) {
      us4 c;
      c[0] = f2bf(v[ch][i].x); c[1] = f2bf(v[ch][i].y);
      c[2] = f2bf(v[ch][i].z); c[3] = f2bf(v[ch][i].w);
      *(us4*)&xs[ch][lr * XSTR2 + lc + i * 4] = c;
    }
  __syncthreads();
  {
    const int wd = tid >> 1, wt = (tid & 1) * 16;
    #pragma unroll
    for (int ch = 0; ch < 2; ch++) {
      us8 o0, o1;
      #pragma unroll
      for (int k = 0; k < 8; k++) {
        o0[k] = xs[ch][(wt + k) * XSTR2 + wd];
        o1[k] = xs[ch][(wt + 8 + k) * XSTR2 + wd];
      }
      unsigned short* xo = xt + ((size_t)b * D_ + d0 + ch * 128 + wd) * T_ + t0;
      *(us8*)(xo + wt) = o0;
      *(us8*)(xo + wt + 8) = o1;
    }
  }
  f32x4 acc = {0.f, 0.f, 0.f, 0.f};
  #pragma unroll
  for (int ch = 0; ch < 2; ch++)
    #pragma unroll
    for (int ks = 0; ks < 4; ks++) {
      short8 af = *(const short8*)&xs[ch][(Mt * 16 + m) * XSTR2 + ks * 32 + quad * 8];
      short8 bf = *(const short8*)(Ut + (size_t)(Nt * 16 + m) * D_ + d0 + ch * 128 + ks * 32 + quad * 8);
      acc = __builtin_amdgcn_mfma_f32_16x16x32_bf16(af, bf, acc, 0, 0, 0);
    }
  float* yp = y_part + ((size_t)(slab * B_ + b) * T_ + t0 + Mt * 16 + quad * 4) * R_ + Nt * 16 + m;
  #pragma unroll
  for (int k = 0; k < 4; k++) yp[(size_t)k * R_] = acc[k];
}

// ---------------- reduce: y = sum_s y_part; ybf (exp2 scale), nsq -----------
__global__ __launch_bounds__(256)
void geo_reduce(const float* __restrict__ y_part, unsigned short* __restrict__ ybf,
                float* __restrict__ nsq) {
  const int tid = threadIdx.x;
  const size_t row = (size_t)blockIdx.x * 32 + (tid >> 3);
  const int r0 = (tid & 7) * 4;
  f32x4 v = {0.f, 0.f, 0.f, 0.f};
  #pragma unroll
  for (int s = 0; s < 4; s++) {
    f32x4 p = *(const f32x4*)(y_part + ((size_t)s * B_ * T_ + row) * R_ + r0);
    #pragma unroll
    for (int k = 0; k < 4; k++) v[k] += p[k];
  }
  us4 pk;
  float part = 0.f;
  #pragma unroll
  for (int k = 0; k < 4; k++) {
    pk[k] = f2bf(S2L * v[k]);
    float b = bf2f(pk[k]);             // exactly what fused will dot
    part += b * b;
  }
  *(us4*)(ybf + row * R_ + r0) = pk;
  part += __shfl_xor(part, 1, 64);
  part += __shfl_xor(part, 2, 64);
  part += __shfl_xor(part, 4, 64);
  if ((tid & 7) == 0) nsq[row] = 0.5f * part;
}

// ---------------- fused scores + PV ----------------
// grid (32 t-tiles * 4 d-tiles, 1, B). Per 64-j tile: async-stage 256dx64j xt
// tile (overlapped by QK), QK^T with A=Yj (wave w owns 16 j), C row=j col=t ->
// lane packs 4 consecutive-j p's into one b64 write; 32 PV MFMAs.
__global__ __launch_bounds__(256)
void geo_fused(const unsigned short* __restrict__ ybf,
               const float* __restrict__ nsq,
               const unsigned short* __restrict__ xt,
               float* __restrict__ out) {
  __shared__ unsigned short XtS[TD * TJ];      // 32 KB, [d][slot^d] swizzled
  __shared__ unsigned short Pbuf[TT * PSTR];   // 9 KB, P rows (A-frag layout)
  __shared__ float lred[4][TT];                // per-wave row sums
  const int b = blockIdx.z;
  const int dt = blockIdx.x & 3, tt = blockIdx.x >> 2;
  const int t0 = tt * TT, d0 = dt * TD;
  const int tid = threadIdx.x, w = tid >> 6, lane = tid & 63;
  const int m = lane & 15, quad = lane >> 4;
  const int srow = lane >> 3, sslot = lane & 7;
  const unsigned short* yb = ybf + (size_t)b * T_ * R_;
  const float* nb = nsq + (size_t)b * T_;
  const unsigned short* xtb = xt + ((size_t)b * D_ + d0) * T_;

  // B-frags: Yt for the 4 t-blocks (lane m = t col); nt scalar per s
  short8 bt[4]; float ntv[4];
  #pragma unroll
  for (int s = 0; s < 4; s++) {
    bt[s]  = *(const short8*)(yb + (size_t)(t0 + s * 16 + m) * R_ + quad * 8);
    ntv[s] = nb[t0 + s * 16 + m];
  }
  f32x4 acc[4][4];
  float lsum[4] = {0.f, 0.f, 0.f, 0.f};
  #pragma unroll
  for (int s = 0; s < 4; s++)
    #pragma unroll
    for (int nt = 0; nt < 4; nt++)
      acc[s][nt] = (f32x4){0.f, 0.f, 0.f, 0.f};

  for (int j0 = 0; j0 < T_; j0 += TJ) {
    if (j0) __syncthreads();   // prev PV done: safe to overwrite XtS/Pbuf
    // ---- stage xt tile (async; QK below overlaps the latency) ----
    #pragma unroll
    for (int cc = 0; cc < 8; cc++) {
      const int rd = w * 64 + cc * 8 + srow;
      const int gs = sslot ^ (rd & 7);
      __builtin_amdgcn_global_load_lds(
          (const __attribute__((address_space(1))) void*)(xtb + (size_t)rd * T_ + j0 + gs * 8),
          (__attribute__((address_space(3))) void*)(XtS + (w * 64 + cc * 8) * 64),
          16, 0, 0);
    }
    // ---- QK^T: A = Yj (wave w's 16 j rows), B = Yt[s] ----
    short8 aj = *(const short8*)(yb + (size_t)(j0 + w * 16 + m) * R_ + quad * 8);
    f32x4 njv = *(const f32x4*)(nb + j0 + w * 16 + quad * 4);
    #pragma unroll
    for (int s = 0; s < 4; s++) {
      f32x4 z = {0.f, 0.f, 0.f, 0.f};
      f32x4 c = __builtin_amdgcn_mfma_f32_16x16x32_bf16(aj, bt[s], z, 0, 0, 0);
      us4 pk;
      float ls = 0.f;
      #pragma unroll
      for (int r = 0; r < 4; r++) {
        float p = __builtin_exp2f(c[r] - njv[r] - ntv[s]);   // native v_exp_f32
        ls += p;
        pk[r] = f2bf(p);
      }
      lsum[s] += ls;
      // lane's t = s*16+m, j = w*16+quad*4..+3 -> one 8B write, <=2-way banks
      *(us4*)(Pbuf + (s * 16 + m) * PSTR + w * 16 + quad * 4) = pk;
    }
    __syncthreads();   // XtS staged (vmcnt drained) + Pbuf visible
    // ---- PV: acc[s][nt] += P[s-th 16t][64j] @ X[64j][w's nt-th 16d] ----
    short8 bx[4][2];
    #pragma unroll
    for (int nt = 0; nt < 4; nt++) {
      const int dloc = w * 64 + nt * 16 + m;
      #pragma unroll
      for (int ks = 0; ks < 2; ks++)
        bx[nt][ks] = *(const short8*)(XtS + dloc * 64 + (((ks * 4 + quad) ^ (dloc & 7)) * 8));
    }
    #pragma unroll
    for (int s = 0; s < 4; s++) {
      short8 a0 = *(const short8*)(Pbuf + (s * 16 + m) * PSTR + quad * 8);
      short8 a1 = *(const short8*)(Pbuf + (s * 16 + m) * PSTR + 32 + quad * 8);
      #pragma unroll
      for (int nt = 0; nt < 4; nt++) {
        acc[s][nt] = __builtin_amdgcn_mfma_f32_16x16x32_bf16(a0, bx[nt][0], acc[s][nt], 0, 0, 0);
        acc[s][nt] = __builtin_amdgcn_mfma_f32_16x16x32_bf16(a1, bx[nt][1], acc[s][nt], 0, 0, 0);
      }
    }
  }
  // ---- l: lane holds sum for t=s*16+m over its j-range; reduce quads+waves --
  #pragma unroll
  for (int s = 0; s < 4; s++) {
    float v = lsum[s];
    v += __shfl_xor(v, 16, 64);
    v += __shfl_xor(v, 32, 64);
    lsum[s] = v;
  }
  if (quad == 0) {
    #pragma unroll
    for (int s = 0; s < 4; s++) lred[w][s * 16 + m] = lsum[s];
  }
  __syncthreads();
  float* ob = out + ((size_t)b * T_ + t0) * D_ + d0;
  #pragma unroll
  for (int s = 0; s < 4; s++) {
    f32x4 lt = *(const f32x4*)&lred[0][s * 16 + quad * 4];
    #pragma unroll
    for (int ww = 1; ww < 4; ww++) {
      f32x4 lv = *(const f32x4*)&lred[ww][s * 16 + quad * 4];
      #pragma unroll
      for (int r = 0; r < 4; r++) lt[r] += lv[r];
    }
    f32x4 inv;
    #pragma unroll
    for (int r = 0; r < 4; r++) inv[r] = 1.f / lt[r];
    #pragma unroll
    for (int nt = 0; nt < 4; nt++)
      #pragma unroll
      for (int r = 0; r < 4; r++)
        ob[(size_t)(s * 16 + quad * 4 + r) * D_ + w * 64 + nt * 16 + m] =
            acc[s][nt][r] * inv[r];
  }
}

extern "C" void kernel_launch(void* const* d_in, const int* in_sizes, int n_in,
                              void* d_out, int out_size, void* d_ws, size_t ws_size,
                              hipStream_t stream) {
  const float* x = (const float*)d_in[0];
  const float* U = (const float*)d_in[1];
  float* out = (float*)d_out;

  const size_t xt_b  = (size_t)B_ * D_ * T_ * 2;       // 16 MB
  const size_t ybf_b = (size_t)B_ * T_ * R_ * 2;       // 512 KB
  const size_t nsq_b = (size_t)B_ * T_ * 4;
  const size_t ut_b  = (size_t)D_ * R_ * 2;            // 64 KB
  const size_t yp_b  = (size_t)4 * B_ * T_ * R_ * 4;   // 4 MB

  char* wp = (char*)d_ws;
  unsigned short* xtp = (unsigned short*)wp;           wp += xt_b;
  unsigned short* ybf = (unsigned short*)wp;           wp += ybf_b;
  float* nsq = (float*)wp;                             wp += nsq_b;
  unsigned short* Utp = (unsigned short*)wp;           wp += ut_b;
  float* ypart = (float*)wp;                           wp += yp_b;
  (void)ws_size;

  hipLaunchKernelGGL(geo_ut, dim3(D_ / 128), dim3(256), 0, stream, U, Utp);
  hipLaunchKernelGGL(geo_prep, dim3(T_ / 32, B_, 4), dim3(256), 0, stream,
                     x, Utp, xtp, ypart);
  hipLaunchKernelGGL(geo_reduce, dim3(B_ * T_ / 32), dim3(256), 0, stream,
                     ypart, ybf, nsq);
  hipLaunchKernelGGL(geo_fused, dim3((T_ / TT) * (D_ / TD), 1, B_), dim3(256), 0, stream,
                     ybf, nsq, xtp, out);
}